// Round 16
// baseline (99.910 us; speedup 1.0000x reference)
//
#include <hip/hip_runtime.h>

#define BB 2
#define NN 16384
#define KK 4096
#define CC 128
#define SS 32
#define BKK (BB * KK)

typedef float vfloat4 __attribute__((ext_vector_type(4)));

// ---------------------------------------------------------------------------
// Kernel A: transpose features [B][C][N] -> [B][N][C] + fused xyzw prep.
// float4-vectorized on BOTH global sides. xyzw prep float exprs UNCHANGED
// (absmax 0.0, rounds 2-14).
// ---------------------------------------------------------------------------
__global__ __launch_bounds__(256) void transpose_prep_kernel(
    const float* __restrict__ feat, const float* __restrict__ xyz,
    float* __restrict__ feat_t, float* __restrict__ xyzw)
{
    __shared__ float tile[64][133];
    const int b  = blockIdx.x >> 8;          // NN/64 = 256 tiles per batch
    const int n0 = (blockIdx.x & 255) * 64;
    const int t  = threadIdx.x;

    if (t < 64) {
        const int i = b * NN + n0 + t;
        const float* p = xyz + (size_t)i * 3;
        const float x = p[0], y = p[1], z = p[2];
        const float pp = __fadd_rn(__fadd_rn(__fmul_rn(x, x), __fmul_rn(y, y)),
                                   __fmul_rn(z, z));
        vfloat4 v = {x, y, z, pp};
        *(vfloat4*)(xyzw + (size_t)i * 4) = v;
    }

    // Read: 2048 float4 loads (c 0..127, n4 0..15), 8 iters x 256 threads.
#pragma unroll
    for (int i = 0; i < 8; ++i) {
        const int li = i * 256 + t;
        const int c  = li >> 4;
        const int n4 = (li & 15) * 4;
        const vfloat4 v = *(const vfloat4*)(feat + ((size_t)b * CC + c) * NN + n0 + n4);
        tile[n4 + 0][c] = v.x;
        tile[n4 + 1][c] = v.y;
        tile[n4 + 2][c] = v.z;
        tile[n4 + 3][c] = v.w;
    }
    __syncthreads();

    // Write: 2048 float4 stores (n 0..63, c4 0..31), 8 iters x 256 threads.
#pragma unroll
    for (int i = 0; i < 8; ++i) {
        const int li = i * 256 + t;
        const int n  = li >> 5;
        const int c4 = (li & 31) * 4;
        vfloat4 v;
        v.x = tile[n][c4 + 0];
        v.y = tile[n][c4 + 1];
        v.z = tile[n][c4 + 2];
        v.w = tile[n][c4 + 3];
        *(vfloat4*)(feat_t + ((size_t)(b * NN + n0 + n)) * CC + c4) = v;
    }
}

// ---------------------------------------------------------------------------
// Kernel S: query sort — FIXED two-level key (round-15 bug: single-level key
// mixed batches within a block, corrupting the shared LDS tile in ball v5).
// bucket = (b<<6) | min(63, |q|^2 * 8): all 4096 batch-0 queries precede all
// batch-1 queries; 4096 % 4 == 0 -> every ball block is batch-uniform.
// Output-order-invariant; key fast-math affects grouping quality only.
// ---------------------------------------------------------------------------
__global__ __launch_bounds__(1024) void qsort_kernel(
    const float* __restrict__ new_xyz,   // [B][K][3]
    int* __restrict__ qmap)              // [BKK]
{
    __shared__ int hist[128];
    __shared__ int base[128];
    __shared__ unsigned char bk[BKK];    // 8 KB

    const int t = threadIdx.x;
    if (t < 128) hist[t] = 0;
    __syncthreads();

#pragma unroll
    for (int c = 0; c < BKK / 1024; ++c) {
        const int q = c * 1024 + t;
        const int b = q >> 12;                       // K = 4096
        const float* p = new_xyz + (size_t)q * 3;
        const float qq = p[0] * p[0] + p[1] * p[1] + p[2] * p[2];
        int bkt = (int)(qq * 8.0f);
        bkt = bkt > 63 ? 63 : bkt;
        bkt |= (b << 6);                             // batch-major
        bk[q] = (unsigned char)bkt;
        atomicAdd(&hist[bkt], 1);
    }
    __syncthreads();

    if (t == 0) {
        int s = 0;
#pragma unroll
        for (int i = 0; i < 128; ++i) { base[i] = s; s += hist[i]; }
    }
    __syncthreads();

#pragma unroll
    for (int c = 0; c < BKK / 1024; ++c) {
        const int q = c * 1024 + t;
        const int pos = atomicAdd(&base[bk[q]], 1);
        qmap[pos] = q;
    }
}

// ---------------------------------------------------------------------------
// Kernel B: ball query v5 = LDS-shared chunks + batch-uniform sorted blocks.
// All 4 waves of a block now share one batch's xyzw (invariant restored) AND
// have similar scan lengths (sort kills the max-of-4-iid inflation).
// Float exprs EXACTLY match reference -> absmax 0.0. Do not alter.
// ---------------------------------------------------------------------------
__global__ __launch_bounds__(256) void ball_query_kernel(
    const float* __restrict__ xyzw,      // [B][N][4]
    const float* __restrict__ new_xyz,   // [B][K][3]
    const int* __restrict__ qmap,        // [BKK]
    int* __restrict__ idx_buf)           // [BKK][S]
{
    __shared__ vfloat4 pts[256];         // 4 KB chunk tile

    const int t    = threadIdx.x;
    const int wave = t >> 6;
    const int lane = t & 63;
    const int qi   = qmap[blockIdx.x * 4 + wave];
    const int b    = qi >> 12;                   // block-uniform (batch-major sort)
    const int k    = qi & (KK - 1);

    const float R2 = (float)(0.4 * 0.4);

    const float* q = new_xyz + (size_t)(b * KK + k) * 3;
    const float qx = q[0], qy = q[1], qz = q[2];
    const float qq = __fadd_rn(__fadd_rn(__fmul_rn(qx, qx), __fmul_rn(qy, qy)),
                               __fmul_rn(qz, qz));

    const vfloat4* xw = (const vfloat4*)xyzw + (size_t)b * NN;
    int* out = idx_buf + (size_t)qi * SS;

    int cnt = 0;

    pts[t] = xw[t];
    __syncthreads();

    for (int base = 0; base < NN; base += 256) {
        const int nb = (base + 256 < NN) ? base + 256 : 0;   // clamp; values unused
        const vfloat4 nxt = xw[nb + t];

        if (cnt < SS) {
            vfloat4 v0 = pts[lane];
            vfloat4 v1 = pts[64 + lane];
            vfloat4 v2 = pts[128 + lane];
            vfloat4 v3 = pts[192 + lane];

            auto d2test = [&](vfloat4 v) -> bool {
                const float dot = __fadd_rn(
                    __fadd_rn(__fmul_rn(qx, v.x), __fmul_rn(qy, v.y)),
                    __fmul_rn(qz, v.z));
                const float d2 = __fsub_rn(__fadd_rn(qq, v.w), __fmul_rn(2.0f, dot));
                return d2 < R2;
            };

            const bool i0 = d2test(v0);
            const bool i1 = d2test(v1);
            const bool i2 = d2test(v2);
            const bool i3 = d2test(v3);
            const unsigned long long m0 = __ballot(i0);
            const unsigned long long m1 = __ballot(i1);
            const unsigned long long m2 = __ballot(i2);
            const unsigned long long m3 = __ballot(i3);

            const int c0 = cnt;
            const int p0 = __popcll(m0), p1 = __popcll(m1);
            const int p2 = __popcll(m2), p3 = __popcll(m3);
            cnt = c0 + p0 + p1 + p2 + p3;

            if ((m0 | m1 | m2 | m3) != 0ull && c0 < SS) {
                const unsigned long long lt = (1ull << lane) - 1ull;
                int bs = c0;
                if (i0) { const int pos = bs + __popcll(m0 & lt);
                          if (pos < SS) out[pos] = base + lane; }
                bs += p0;
                if (i1) { const int pos = bs + __popcll(m1 & lt);
                          if (pos < SS) out[pos] = base + 64 + lane; }
                bs += p1;
                if (i2) { const int pos = bs + __popcll(m2 & lt);
                          if (pos < SS) out[pos] = base + 128 + lane; }
                bs += p2;
                if (i3) { const int pos = bs + __popcll(m3 & lt);
                          if (pos < SS) out[pos] = base + 192 + lane; }
            }
        }

        if (__syncthreads_and(cnt >= SS)) break;

        pts[t] = nxt;
        __syncthreads();
    }

    const int fill = (cnt > 0) ? out[0] : 0;
    if (lane < SS && lane >= cnt) out[lane] = fill;
}

// ---------------------------------------------------------------------------
// Kernel C: grouping. UNCHANGED single-copy form (G~7us gather + W~24us
// stores, 0 bank conflicts — validated round 10).
// ---------------------------------------------------------------------------
__global__ __launch_bounds__(256) void group_kernel(
    const float* __restrict__ xyzw,      // [B][N][4]
    const float* __restrict__ new_xyz,   // [B][K][3]
    const float* __restrict__ feat_t,    // [B][N][C]
    const int*   __restrict__ idx_buf,   // [B*K][S]
    float* __restrict__ out)             // [B][3][K][S] ++ [B][C][K][S]
{
    __shared__ float tile[SS * CC];      // 32 rows x 512B, linear, chunk-swizzled
    __shared__ float txyz[3][SS];

    const int t    = threadIdx.x;
    const int l    = t & 63;
    const int w    = t >> 6;             // wave 0..3
    const int bk   = blockIdx.x;
    const int b    = bk >> 12;
    const int k    = bk & (KK - 1);
    const int half = l >> 5;             // 0..1
    const int cl   = l & 31;             // chunk slot within row

#pragma unroll
    for (int p = 0; p < 4; ++p) {
        const int r = 8 * w + 2 * p;                 // wave-uniform row base
        const int s = r + half;
        const int n = idx_buf[bk * SS + s];
        const int chunk = cl ^ ((s >> 2) & 7);
        const float* src = feat_t + ((size_t)(b * NN + n)) * CC + 4 * chunk;
        __builtin_amdgcn_global_load_lds(
            (const __attribute__((address_space(1))) void*)src,
            (__attribute__((address_space(3))) void*)(tile + r * CC),
            16, 0, 0);
    }

    if (t < SS) {
        const int n = idx_buf[bk * SS + t];
        const float* q = new_xyz + (size_t)bk * 3;
        const vfloat4 wv = *((const vfloat4*)xyzw + (size_t)b * NN + n);
        txyz[0][t] = (wv.x - q[0]) / 0.4f;
        txyz[1][t] = (wv.y - q[1]) / 0.4f;
        txyz[2][t] = (wv.z - q[2]) / 0.4f;
    }

    __syncthreads();   // drains vmcnt(0): all DMAs + txyz visible

    float* out_xyz  = out;
    float* out_feat = out + (size_t)BB * 3 * KK * SS;

    const int sq = t & 7;
    const int c0 = t >> 3;               // 0..31
#pragma unroll
    for (int p = 0; p < 4; ++p) {
        const int c  = c0 + 32 * p;
        const int co = (((c >> 2) ^ sq) << 2) + (c & 3);   // un-swizzled col
        vfloat4 v;
        v.x = tile[(4 * sq + 0) * CC + co];
        v.y = tile[(4 * sq + 1) * CC + co];
        v.z = tile[(4 * sq + 2) * CC + co];
        v.w = tile[(4 * sq + 3) * CC + co];
        __builtin_nontemporal_store(
            v, (vfloat4*)(out_feat + (((size_t)(b * CC + c) * KK + k) * SS + 4 * sq)));
    }

    if (t < 24) {
        const int d   = t >> 3;
        const int sq2 = t & 7;
        const vfloat4 v = *(vfloat4*)&txyz[d][4 * sq2];
        __builtin_nontemporal_store(
            v, (vfloat4*)(out_xyz + (((size_t)(b * 3 + d) * KK + k) * SS + 4 * sq2)));
    }
}

extern "C" void kernel_launch(void* const* d_in, const int* in_sizes, int n_in,
                              void* d_out, int out_size, void* d_ws, size_t ws_size,
                              hipStream_t stream) {
    const float* xyz     = (const float*)d_in[0];   // [2][16384][3]
    const float* new_xyz = (const float*)d_in[1];   // [2][4096][3]
    const float* feat    = (const float*)d_in[2];   // [2][128][16384]
    float* out = (float*)d_out;

    // Workspace: idx_buf 1MB | xyzw 0.5MB | feat_t 16MB | qmap 32KB
    int*   idx_buf = (int*)d_ws;
    float* xyzw    = (float*)((char*)d_ws + (1 << 20));
    float* feat_t  = (float*)((char*)d_ws + (1 << 20) + (512 << 10));
    int*   qmap    = (int*)((char*)d_ws + (1 << 20) + (512 << 10) + (CC * NN * BB) * 4);

    transpose_prep_kernel<<<dim3(BB * (NN / 64)), dim3(256), 0, stream>>>(
        feat, xyz, feat_t, xyzw);

    qsort_kernel<<<dim3(1), dim3(1024), 0, stream>>>(new_xyz, qmap);

    ball_query_kernel<<<dim3(BKK / 4), dim3(256), 0, stream>>>(
        xyzw, new_xyz, qmap, idx_buf);

    group_kernel<<<dim3(BKK), dim3(256), 0, stream>>>(
        xyzw, new_xyz, feat_t, idx_buf, out);
}